// Round 8
// baseline (310.461 us; speedup 1.0000x reference)
//
#include <hip/hip_runtime.h>
#include <hip/hip_fp16.h>

#define NN 100000
#define NE 3200000
#define DF 128
#define HID 32
#define NC 2
#define NB 391     // ceil(NN/256): blocks for node-parallel kernels
#define NBUK 391   // buckets of 256 nodes: bucket = dst >> 8
#define EB 2048    // edges per block in k_hist/k_part (1563 blocks)
#define NEB 1563   // ceil(NE/EB)
#define PL (NN * 16)  // halves per h1 channel-plane

// ws layout (4-byte words):
// [0, NN)                 dis (float): rsqrt(deg+1)
// [NN, 2NN)               rofs (int): global row starts (CSR)
// [2NN, 2NN+400)          btot (uint): bucket totals
// [2NN+400, 2NN+800)      bstart (int): bucket starts (392 used)
// [2NN+800, 2NN+1200)     cursor (int): bucket cursors (mutated by k_part)
// [2NN+1200, 4NN+1200)    h2 (float [NN,2])
// [4NN+1200, +NE)         csr (int): src indices grouped by dst
// [4NN+1200+NE, +NE)      scr (packed edges, NE words); after k_build consumes it,
//                         h1 (2 planes of [NN,16] halves = 16NN words) overwrites it
// total 4NN + 2NE + 1200 = 27.2 MB (unchanged)

__global__ void k_z(unsigned* __restrict__ p, int n) {
    int i = blockIdx.x * blockDim.x + threadIdx.x;
    if (i < n) p[i] = 0u;
}

// per-block LDS histogram over buckets -> global bucket totals (non-returning adds)
__global__ __launch_bounds__(256) void k_hist(const int* __restrict__ dst,
                                              unsigned* __restrict__ btot) {
    __shared__ unsigned h[NBUK];
    for (int i = threadIdx.x; i < NBUK; i += 256) h[i] = 0u;
    __syncthreads();
    int base = blockIdx.x * EB;
#pragma unroll
    for (int i = 0; i < EB / 256; ++i) {
        int e = base + i * 256 + threadIdx.x;
        if (e < NE) atomicAdd(&h[dst[e] >> 8], 1u);
    }
    __syncthreads();
    for (int i = threadIdx.x; i < NBUK; i += 256)
        if (h[i]) atomicAdd(&btot[i], h[i]);
}

// single-block exclusive scan of bucket totals -> bstart, cursor
__global__ void k_bscan(const unsigned* __restrict__ btot, int* __restrict__ bstart,
                        int* __restrict__ cursor) {
    __shared__ int sm[512];
    int v = (threadIdx.x < NBUK) ? (int)btot[threadIdx.x] : 0;
    sm[threadIdx.x] = v;
    __syncthreads();
    for (int off = 1; off < 512; off <<= 1) {
        int t = (threadIdx.x >= off) ? sm[threadIdx.x - off] : 0;
        __syncthreads();
        sm[threadIdx.x] += t;
        __syncthreads();
    }
    if (threadIdx.x < NBUK) {
        int excl = sm[threadIdx.x] - v;
        bstart[threadIdx.x] = excl;
        cursor[threadIdx.x] = excl;
    }
    if (threadIdx.x == 0) bstart[NBUK] = NE;
}

// partition edges into bucket regions of scr; packed word = src | (dst&255)<<17
__global__ __launch_bounds__(256) void k_part(const int* __restrict__ eidx,
                                              int* __restrict__ cursor,
                                              unsigned* __restrict__ scr) {
    __shared__ unsigned h[NBUK];
    for (int i = threadIdx.x; i < NBUK; i += 256) h[i] = 0u;
    __syncthreads();
    int base = blockIdx.x * EB;
    int d[EB / 256];
#pragma unroll
    for (int i = 0; i < EB / 256; ++i) {
        int e = base + i * 256 + threadIdx.x;
        d[i] = (e < NE) ? eidx[NE + e] : -1;
        if (d[i] >= 0) atomicAdd(&h[d[i] >> 8], 1u);
    }
    __syncthreads();
    // reserve global space per (block,bucket): one returning atomic per nonzero bin
    for (int i = threadIdx.x; i < NBUK; i += 256) {
        unsigned c = h[i];
        h[i] = c ? atomicAdd((unsigned*)&cursor[i], c) : 0u;
    }
    __syncthreads();
#pragma unroll
    for (int i = 0; i < EB / 256; ++i) {
        int e = base + i * 256 + threadIdx.x;
        if (e < NE) {
            unsigned s = (unsigned)eidx[e];
            unsigned pos = atomicAdd(&h[d[i] >> 8], 1u);   // LDS returning atomic
            scr[pos] = s | ((unsigned)(d[i] & 255) << 17);
        }
    }
}

// one block (512 thr) per bucket: 256-bin LDS histogram -> rofs/dis + ranked scatter
__global__ __launch_bounds__(512) void k_build(const unsigned* __restrict__ scr,
                                               const int* __restrict__ bstart,
                                               int* __restrict__ rofs, float* __restrict__ dis,
                                               int* __restrict__ csr) {
    int b = blockIdx.x;
    int cs = bstart[b], ce = bstart[b + 1];
    int tid = threadIdx.x;
    __shared__ unsigned h[256];
    __shared__ int sm[256];
    if (tid < 256) h[tid] = 0u;
    __syncthreads();
    for (int j = cs + tid; j < ce; j += 512)
        atomicAdd(&h[(scr[j] >> 17) & 255], 1u);
    __syncthreads();
    int v = (tid < 256) ? (int)h[tid] : 0;
    if (tid < 256) sm[tid] = v;
    __syncthreads();
    for (int off = 1; off < 256; off <<= 1) {
        int t = (tid < 256 && tid >= off) ? sm[tid - off] : 0;
        __syncthreads();
        if (tid < 256) sm[tid] += t;
        __syncthreads();
    }
    if (tid < 256) {
        int excl = sm[tid] - v;
        int node = b * 256 + tid;
        if (node < NN) {
            rofs[node] = cs + excl;
            dis[node] = rsqrtf((float)(v + 1));   // +1 = self-loop
        }
        h[tid] = (unsigned)(cs + excl);           // reuse as per-node cursor
    }
    __syncthreads();
    for (int j = cs + tid; j < ce; j += 512) {
        unsigned w = scr[j];
        unsigned pos = atomicAdd(&h[(w >> 17) & 255], 1u);
        csr[pos] = (int)(w & 0x1FFFFu);
    }
}

// h1 = x @ W1, stored fp16 in 2 channel-planes of [NN,16] (each 3.2 MB, per-XCD-L2-sized)
__global__ __launch_bounds__(256) void k_gemm1(const float* __restrict__ x,
                                               const float* __restrict__ W1,
                                               __half* __restrict__ h1) {
    int r = blockIdx.x * blockDim.x + threadIdx.x;
    if (r >= NN) return;
    const float* xr = x + (size_t)r * DF;
    float acc[HID];
#pragma unroll
    for (int c = 0; c < HID; ++c) acc[c] = 0.f;
#pragma unroll
    for (int k = 0; k < DF; k += 4) {
        float4 xv = *reinterpret_cast<const float4*>(xr + k);
#pragma unroll
        for (int c = 0; c < HID; ++c) {
            acc[c] += xv.x * W1[(k + 0) * HID + c];
            acc[c] += xv.y * W1[(k + 1) * HID + c];
            acc[c] += xv.z * W1[(k + 2) * HID + c];
            acc[c] += xv.w * W1[(k + 3) * HID + c];
        }
    }
    __half2 pack[HID / 2];
#pragma unroll
    for (int c = 0; c < HID; c += 2)
        pack[c / 2] = __floats2half2_rn(acc[c], acc[c + 1]);
    const float4* srcp = reinterpret_cast<const float4*>(pack);
    float4* p0 = reinterpret_cast<float4*>(h1 + (size_t)r * 16);
    float4* p1 = reinterpret_cast<float4*>(h1 + (size_t)PL + (size_t)r * 16);
    p0[0] = srcp[0]; p0[1] = srcp[1];   // channels 0-15
    p1[0] = srcp[2]; p1[1] = srcp[3];   // channels 16-31
}

// gather-aggregate layer 1, one 16-channel plane per pass (4 lanes/edge, 8B/lane).
// PASS=0 writes partial h2; PASS=1 accumulates (launch-ordered, race-free).
template <int PASS>
__global__ void k_gather1(const int* __restrict__ rofs, const int* __restrict__ csr,
                          const float* __restrict__ dis, const __half* __restrict__ h1,
                          const float* __restrict__ b1, const float* __restrict__ W2,
                          float* __restrict__ h2) {
    int t = blockIdx.x * blockDim.x + threadIdx.x;
    int r = t >> 2;
    if (r >= NN) return;
    int p = t & 3;
    const __half* plane = h1 + (size_t)PASS * PL;
    int start = rofs[r];
    int end = (r == NN - 1) ? NE : rofs[r + 1];
    float dr = dis[r];
    float a0 = 0.f, a1 = 0.f, a2 = 0.f, a3 = 0.f;
    int j = start;
    for (; j + 1 < end; j += 2) {
        int s0 = csr[j], s1 = csr[j + 1];
        float n0 = dr * dis[s0], n1 = dr * dis[s1];
        const __half2* q0 = reinterpret_cast<const __half2*>(plane + (size_t)s0 * 16 + p * 4);
        const __half2* q1 = reinterpret_cast<const __half2*>(plane + (size_t)s1 * 16 + p * 4);
        float2 u0 = __half22float2(q0[0]), u1 = __half22float2(q0[1]);
        float2 w0 = __half22float2(q1[0]), w1 = __half22float2(q1[1]);
        a0 += u0.x * n0 + w0.x * n1;
        a1 += u0.y * n0 + w0.y * n1;
        a2 += u1.x * n0 + w1.x * n1;
        a3 += u1.y * n0 + w1.y * n1;
    }
    if (j < end) {
        int s0 = csr[j];
        float n0 = dr * dis[s0];
        const __half2* q0 = reinterpret_cast<const __half2*>(plane + (size_t)s0 * 16 + p * 4);
        float2 u0 = __half22float2(q0[0]), u1 = __half22float2(q0[1]);
        a0 += u0.x * n0; a1 += u0.y * n0; a2 += u1.x * n0; a3 += u1.y * n0;
    }
    float self = dr * dr;
    const __half2* qs = reinterpret_cast<const __half2*>(plane + (size_t)r * 16 + p * 4);
    float2 s0v = __half22float2(qs[0]), s1v = __half22float2(qs[1]);
    a0 += s0v.x * self; a1 += s0v.y * self; a2 += s1v.x * self; a3 += s1v.y * self;
    int c = PASS * 16 + p * 4;
    float4 bv = *reinterpret_cast<const float4*>(b1 + c);
    float v0 = fmaxf(a0 + bv.x, 0.f);
    float v1 = fmaxf(a1 + bv.y, 0.f);
    float v2 = fmaxf(a2 + bv.z, 0.f);
    float v3 = fmaxf(a3 + bv.w, 0.f);
    float o0 = v0 * W2[(c + 0) * NC + 0] + v1 * W2[(c + 1) * NC + 0] +
               v2 * W2[(c + 2) * NC + 0] + v3 * W2[(c + 3) * NC + 0];
    float o1 = v0 * W2[(c + 0) * NC + 1] + v1 * W2[(c + 1) * NC + 1] +
               v2 * W2[(c + 2) * NC + 1] + v3 * W2[(c + 3) * NC + 1];
    o0 += __shfl_xor(o0, 1); o1 += __shfl_xor(o1, 1);
    o0 += __shfl_xor(o0, 2); o1 += __shfl_xor(o1, 2);
    if (p == 0) {
        if (PASS == 0) {
            h2[2 * (size_t)r + 0] = o0;
            h2[2 * (size_t)r + 1] = o1;
        } else {
            h2[2 * (size_t)r + 0] += o0;
            h2[2 * (size_t)r + 1] += o1;
        }
    }
}

// gather-aggregate layer 2 (+b2) fused with log_softmax -> out
__global__ void k_gather2(const int* __restrict__ rofs, const int* __restrict__ csr,
                          const float* __restrict__ dis, const float* __restrict__ h2,
                          const float* __restrict__ b2, float* __restrict__ out) {
    int r = blockIdx.x * blockDim.x + threadIdx.x;
    if (r >= NN) return;
    int start = rofs[r];
    int end = (r == NN - 1) ? NE : rofs[r + 1];
    float dr = dis[r];
    float a0 = 0.f, a1 = 0.f;
    for (int j = start; j < end; ++j) {
        int s = csr[j];
        float nrm = dr * dis[s];
        float2 v = *reinterpret_cast<const float2*>(h2 + 2 * (size_t)s);
        a0 += v.x * nrm;
        a1 += v.y * nrm;
    }
    float self = dr * dr;
    float2 hv = *reinterpret_cast<const float2*>(h2 + 2 * (size_t)r);
    float l0 = a0 + hv.x * self + b2[0];
    float l1 = a1 + hv.y * self + b2[1];
    float m = fmaxf(l0, l1);
    float lse = m + logf(expf(l0 - m) + expf(l1 - m));
    out[2 * (size_t)r + 0] = l0 - lse;
    out[2 * (size_t)r + 1] = l1 - lse;
}

extern "C" void kernel_launch(void* const* d_in, const int* in_sizes, int n_in,
                              void* d_out, int out_size, void* d_ws, size_t ws_size,
                              hipStream_t stream) {
    const float* x  = (const float*)d_in[0];
    const int* ei   = (const int*)d_in[1];   // [2, NE] int32
    const float* W1 = (const float*)d_in[2];
    const float* b1 = (const float*)d_in[3];
    const float* W2 = (const float*)d_in[4];
    const float* b2 = (const float*)d_in[5];
    float* out      = (float*)d_out;

    float* ws       = (float*)d_ws;
    float* dis      = ws;
    int* rofs       = (int*)(ws + (size_t)NN);
    unsigned* btot  = (unsigned*)(ws + (size_t)2 * NN);
    int* bstart     = (int*)(ws + (size_t)2 * NN + 400);
    int* cursor     = (int*)(ws + (size_t)2 * NN + 800);
    float* h2       = ws + (size_t)2 * NN + 1200;
    int* csr        = (int*)(ws + (size_t)4 * NN + 1200);
    unsigned* scr   = (unsigned*)(ws + (size_t)4 * NN + 1200 + NE);  // NE words
    __half* h1      = (__half*)scr;  // 2 planes x 16NN halves; written after k_build

    k_z<<<2, 256, 0, stream>>>(btot, NBUK);
    k_hist<<<NEB, 256, 0, stream>>>(ei + NE, btot);
    k_bscan<<<1, 512, 0, stream>>>(btot, bstart, cursor);
    k_part<<<NEB, 256, 0, stream>>>(ei, cursor, scr);
    k_build<<<NBUK, 512, 0, stream>>>(scr, bstart, rofs, dis, csr);
    k_gemm1<<<NB, 256, 0, stream>>>(x, W1, h1);
    k_gather1<0><<<(NN * 4 + 255) / 256, 256, 0, stream>>>(rofs, csr, dis, h1, b1, W2, h2);
    k_gather1<1><<<(NN * 4 + 255) / 256, 256, 0, stream>>>(rofs, csr, dis, h1, b1, W2, h2);
    k_gather2<<<NB, 256, 0, stream>>>(rofs, csr, dis, h2, b2, out);
}

// Round 9
// 227.851 us; speedup vs baseline: 1.3626x; 1.3626x over previous
//
#include <hip/hip_runtime.h>
#include <hip/hip_fp16.h>

#define NN 100000
#define NE 3200000
#define DF 128
#define HID 32
#define NC 2
#define NB 391     // ceil(NN/256): blocks for node-parallel kernels
#define NBUK 391   // buckets of 256 nodes: bucket = dst >> 8
#define HEB 2048   // edges per block in k_hist (1563 blocks)
#define PEB 8192   // edges per block in k_part (391 blocks)

// ws layout (4-byte words):
// [0, NN)                 dis (float): rsqrt(deg+1)
// [NN, 2NN)               rofs (int): global row starts (CSR)
// [2NN, 2NN+400)          btot (uint): bucket totals
// [2NN+400, 2NN+800)      bstart (int): bucket starts (392 used)
// [2NN+800, 2NN+1200)     cursor (int): bucket cursors (mutated by k_part)
// [2NN+1200, 4NN+1200)    h2 (float [NN,2])
// [4NN+1200, +NE)         csr (int): src indices grouped by dst
// [4NN+1200+NE, +NE)      scr (packed edges, NE words); after k_build consumes it,
//                         h1 (fp16 [NN,32] = 16NN words) overwrites it
// total 4NN + 2NE + 1200 = 27.2 MB

__global__ void k_z(unsigned* __restrict__ p, int n) {
    int i = blockIdx.x * blockDim.x + threadIdx.x;
    if (i < n) p[i] = 0u;
}

// per-block LDS histogram over buckets -> global bucket totals (non-returning adds)
__global__ __launch_bounds__(256) void k_hist(const int* __restrict__ dst,
                                              unsigned* __restrict__ btot) {
    __shared__ unsigned h[NBUK];
    for (int i = threadIdx.x; i < NBUK; i += 256) h[i] = 0u;
    __syncthreads();
    int base = blockIdx.x * HEB;
#pragma unroll
    for (int i = 0; i < HEB / 256; ++i) {
        int e = base + i * 256 + threadIdx.x;
        if (e < NE) atomicAdd(&h[dst[e] >> 8], 1u);
    }
    __syncthreads();
    for (int i = threadIdx.x; i < NBUK; i += 256)
        if (h[i]) atomicAdd(&btot[i], h[i]);
}

// single-block exclusive scan of bucket totals -> bstart, cursor
__global__ void k_bscan(const unsigned* __restrict__ btot, int* __restrict__ bstart,
                        int* __restrict__ cursor) {
    __shared__ int sm[512];
    int v = (threadIdx.x < NBUK) ? (int)btot[threadIdx.x] : 0;
    sm[threadIdx.x] = v;
    __syncthreads();
    for (int off = 1; off < 512; off <<= 1) {
        int t = (threadIdx.x >= off) ? sm[threadIdx.x - off] : 0;
        __syncthreads();
        sm[threadIdx.x] += t;
        __syncthreads();
    }
    if (threadIdx.x < NBUK) {
        int excl = sm[threadIdx.x] - v;
        bstart[threadIdx.x] = excl;
        cursor[threadIdx.x] = excl;
    }
    if (threadIdx.x == 0) bstart[NBUK] = NE;
}

// LDS-staged partition: sort block's edges by bucket in LDS, then coalesced copy-out.
// packed word = src | (dst&255)<<17
__global__ __launch_bounds__(512) void k_part(const int* __restrict__ eidx,
                                              int* __restrict__ cursor,
                                              unsigned* __restrict__ scr) {
    __shared__ unsigned hist[NBUK];      // per-bucket counts
    __shared__ unsigned lofs[NBUK + 1];  // exclusive scan (+ sentinel = total)
    __shared__ unsigned aux[NBUK];       // local cursor, then global base
    __shared__ unsigned stage[PEB];      // bucket-sorted packed edges (32 KB)
    __shared__ int sm[512];
    int tid = threadIdx.x;
    int base = blockIdx.x * PEB;

    for (int i = tid; i < NBUK; i += 512) hist[i] = 0u;
    __syncthreads();

    int s[PEB / 512], d[PEB / 512];
#pragma unroll
    for (int i = 0; i < PEB / 512; ++i) {
        int e = base + i * 512 + tid;
        if (e < NE) {
            s[i] = eidx[e];
            d[i] = eidx[NE + e];
            atomicAdd(&hist[d[i] >> 8], 1u);
        } else d[i] = -1;
    }
    __syncthreads();

    // 512-wide Hillis-Steele inclusive scan of the 391 counts
    int v = (tid < NBUK) ? (int)hist[tid] : 0;
    sm[tid] = v;
    __syncthreads();
    for (int off = 1; off < 512; off <<= 1) {
        int t = (tid >= off) ? sm[tid - off] : 0;
        __syncthreads();
        sm[tid] += t;
        __syncthreads();
    }
    if (tid < NBUK) {
        unsigned excl = (unsigned)(sm[tid] - v);
        lofs[tid] = excl;
        aux[tid] = excl;      // local cursor
    }
    if (tid == 0) lofs[NBUK] = (unsigned)sm[511];  // total valid edges
    __syncthreads();

    // LDS scatter: bucket-sorted staging
#pragma unroll
    for (int i = 0; i < PEB / 512; ++i) {
        if (d[i] >= 0) {
            unsigned lpos = atomicAdd(&aux[d[i] >> 8], 1u);
            stage[lpos] = (unsigned)s[i] | ((unsigned)(d[i] & 255) << 17);
        }
    }
    __syncthreads();

    // reserve global space: one returning atomic per nonzero bucket
    for (int i = tid; i < NBUK; i += 512) {
        unsigned c = hist[i];
        aux[i] = c ? (unsigned)atomicAdd((unsigned*)&cursor[i], c) : 0u;
    }
    __syncthreads();

    // coalesced copy-out: bin of word j via binary search over lofs
    int total = (int)lofs[NBUK];
    for (int j = tid; j < total; j += 512) {
        int lo = 0, hi = NBUK - 1;
        while (lo < hi) {
            int mid = (lo + hi + 1) >> 1;
            if ((int)lofs[mid] <= j) lo = mid; else hi = mid - 1;
        }
        scr[aux[lo] + (unsigned)(j - (int)lofs[lo])] = stage[j];
    }
}

// one block per bucket: 256-bin LDS histogram -> rofs/dis + ranked scatter into csr
__global__ __launch_bounds__(256) void k_build(const unsigned* __restrict__ scr,
                                               const int* __restrict__ bstart,
                                               int* __restrict__ rofs, float* __restrict__ dis,
                                               int* __restrict__ csr) {
    int b = blockIdx.x;
    int cs = bstart[b], ce = bstart[b + 1];
    __shared__ unsigned h[256];
    __shared__ int sm[256];
    h[threadIdx.x] = 0u;
    __syncthreads();
    for (int j = cs + threadIdx.x; j < ce; j += 256)
        atomicAdd(&h[(scr[j] >> 17) & 255], 1u);
    __syncthreads();
    int v = (int)h[threadIdx.x];
    sm[threadIdx.x] = v;
    __syncthreads();
    for (int off = 1; off < 256; off <<= 1) {
        int t = (threadIdx.x >= off) ? sm[threadIdx.x - off] : 0;
        __syncthreads();
        sm[threadIdx.x] += t;
        __syncthreads();
    }
    int excl = sm[threadIdx.x] - v;
    int node = b * 256 + threadIdx.x;
    if (node < NN) {
        rofs[node] = cs + excl;
        dis[node] = rsqrtf((float)(v + 1));   // +1 = self-loop
    }
    __syncthreads();
    h[threadIdx.x] = (unsigned)(cs + excl);   // reuse as per-node cursor
    __syncthreads();
    for (int j = cs + threadIdx.x; j < ce; j += 256) {
        unsigned w = scr[j];
        unsigned pos = atomicAdd(&h[(w >> 17) & 255], 1u);
        csr[pos] = (int)(w & 0x1FFFFu);
    }
}

// h1 = x @ W1, stored fp16 interleaved [NN,32] (64B row = one cache line)
__global__ __launch_bounds__(256) void k_gemm1(const float* __restrict__ x,
                                               const float* __restrict__ W1,
                                               __half* __restrict__ h1) {
    int r = blockIdx.x * blockDim.x + threadIdx.x;
    if (r >= NN) return;
    const float* xr = x + (size_t)r * DF;
    float acc[HID];
#pragma unroll
    for (int c = 0; c < HID; ++c) acc[c] = 0.f;
#pragma unroll
    for (int k = 0; k < DF; k += 4) {
        float4 xv = *reinterpret_cast<const float4*>(xr + k);
#pragma unroll
        for (int c = 0; c < HID; ++c) {
            acc[c] += xv.x * W1[(k + 0) * HID + c];
            acc[c] += xv.y * W1[(k + 1) * HID + c];
            acc[c] += xv.z * W1[(k + 2) * HID + c];
            acc[c] += xv.w * W1[(k + 3) * HID + c];
        }
    }
    __half2 pack[HID / 2];
#pragma unroll
    for (int c = 0; c < HID; c += 2)
        pack[c / 2] = __floats2half2_rn(acc[c], acc[c + 1]);
    float4* dstp = reinterpret_cast<float4*>(h1 + (size_t)r * HID);
    const float4* srcp = reinterpret_cast<const float4*>(pack);
#pragma unroll
    for (int i = 0; i < 4; ++i) dstp[i] = srcp[i];
}

// gather-aggregate layer 1: 4 lanes/edge x float4 (full 64B fp16 row), 4-edge unroll.
// fused +b1 / relu / @W2 / 4-lane reduce -> h2
__global__ void k_gather1(const int* __restrict__ rofs, const int* __restrict__ csr,
                          const float* __restrict__ dis, const __half* __restrict__ h1,
                          const float* __restrict__ b1, const float* __restrict__ W2,
                          float* __restrict__ h2) {
    int t = blockIdx.x * blockDim.x + threadIdx.x;
    int r = t >> 2;
    if (r >= NN) return;
    int p = t & 3;
    const float4* hv = reinterpret_cast<const float4*>(h1);
    int start = rofs[r];
    int end = (r == NN - 1) ? NE : rofs[r + 1];
    float dr = dis[r];
    float a[8];
#pragma unroll
    for (int k = 0; k < 8; ++k) a[k] = 0.f;

#define ACC4(q, n)                                                        \
    {                                                                     \
        const __half2* hp = reinterpret_cast<const __half2*>(&(q));       \
        _Pragma("unroll") for (int k = 0; k < 4; ++k) {                   \
            float2 f = __half22float2(hp[k]);                             \
            a[2 * k] += f.x * (n);                                        \
            a[2 * k + 1] += f.y * (n);                                    \
        }                                                                 \
    }

    int j = start;
    for (; j + 3 < end; j += 4) {
        int s0 = csr[j], s1 = csr[j + 1], s2 = csr[j + 2], s3 = csr[j + 3];
        float n0 = dr * dis[s0], n1 = dr * dis[s1];
        float n2 = dr * dis[s2], n3 = dr * dis[s3];
        float4 q0 = hv[(size_t)s0 * 4 + p];
        float4 q1 = hv[(size_t)s1 * 4 + p];
        float4 q2 = hv[(size_t)s2 * 4 + p];
        float4 q3 = hv[(size_t)s3 * 4 + p];
        ACC4(q0, n0) ACC4(q1, n1) ACC4(q2, n2) ACC4(q3, n3)
    }
    for (; j < end; ++j) {
        int s0 = csr[j];
        float n0 = dr * dis[s0];
        float4 q0 = hv[(size_t)s0 * 4 + p];
        ACC4(q0, n0)
    }
    float self = dr * dr;
    float4 qs = hv[(size_t)r * 4 + p];
    ACC4(qs, self)
#undef ACC4

    int c = p * 8;
    float4 bl = *reinterpret_cast<const float4*>(b1 + c);
    float4 bh = *reinterpret_cast<const float4*>(b1 + c + 4);
    float vv[8];
    vv[0] = fmaxf(a[0] + bl.x, 0.f); vv[1] = fmaxf(a[1] + bl.y, 0.f);
    vv[2] = fmaxf(a[2] + bl.z, 0.f); vv[3] = fmaxf(a[3] + bl.w, 0.f);
    vv[4] = fmaxf(a[4] + bh.x, 0.f); vv[5] = fmaxf(a[5] + bh.y, 0.f);
    vv[6] = fmaxf(a[6] + bh.z, 0.f); vv[7] = fmaxf(a[7] + bh.w, 0.f);
    float o0 = 0.f, o1 = 0.f;
#pragma unroll
    for (int k = 0; k < 8; ++k) {
        o0 += vv[k] * W2[(c + k) * NC + 0];
        o1 += vv[k] * W2[(c + k) * NC + 1];
    }
    o0 += __shfl_xor(o0, 1); o1 += __shfl_xor(o1, 1);
    o0 += __shfl_xor(o0, 2); o1 += __shfl_xor(o1, 2);
    if (p == 0) {
        h2[2 * (size_t)r + 0] = o0;
        h2[2 * (size_t)r + 1] = o1;
    }
}

// gather-aggregate layer 2 (+b2) fused with log_softmax -> out
__global__ void k_gather2(const int* __restrict__ rofs, const int* __restrict__ csr,
                          const float* __restrict__ dis, const float* __restrict__ h2,
                          const float* __restrict__ b2, float* __restrict__ out) {
    int r = blockIdx.x * blockDim.x + threadIdx.x;
    if (r >= NN) return;
    int start = rofs[r];
    int end = (r == NN - 1) ? NE : rofs[r + 1];
    float dr = dis[r];
    float a0 = 0.f, a1 = 0.f;
    for (int j = start; j < end; ++j) {
        int s = csr[j];
        float nrm = dr * dis[s];
        float2 v = *reinterpret_cast<const float2*>(h2 + 2 * (size_t)s);
        a0 += v.x * nrm;
        a1 += v.y * nrm;
    }
    float self = dr * dr;
    float2 hv = *reinterpret_cast<const float2*>(h2 + 2 * (size_t)r);
    float l0 = a0 + hv.x * self + b2[0];
    float l1 = a1 + hv.y * self + b2[1];
    float m = fmaxf(l0, l1);
    float lse = m + logf(expf(l0 - m) + expf(l1 - m));
    out[2 * (size_t)r + 0] = l0 - lse;
    out[2 * (size_t)r + 1] = l1 - lse;
}

extern "C" void kernel_launch(void* const* d_in, const int* in_sizes, int n_in,
                              void* d_out, int out_size, void* d_ws, size_t ws_size,
                              hipStream_t stream) {
    const float* x  = (const float*)d_in[0];
    const int* ei   = (const int*)d_in[1];   // [2, NE] int32
    const float* W1 = (const float*)d_in[2];
    const float* b1 = (const float*)d_in[3];
    const float* W2 = (const float*)d_in[4];
    const float* b2 = (const float*)d_in[5];
    float* out      = (float*)d_out;

    float* ws       = (float*)d_ws;
    float* dis      = ws;
    int* rofs       = (int*)(ws + (size_t)NN);
    unsigned* btot  = (unsigned*)(ws + (size_t)2 * NN);
    int* bstart     = (int*)(ws + (size_t)2 * NN + 400);
    int* cursor     = (int*)(ws + (size_t)2 * NN + 800);
    float* h2       = ws + (size_t)2 * NN + 1200;
    int* csr        = (int*)(ws + (size_t)4 * NN + 1200);
    unsigned* scr   = (unsigned*)(ws + (size_t)4 * NN + 1200 + NE);  // NE words
    __half* h1      = (__half*)scr;  // 16NN halves; written after k_build consumes scr

    k_z<<<2, 256, 0, stream>>>(btot, NBUK);
    k_hist<<<(NE + HEB - 1) / HEB, 256, 0, stream>>>(ei + NE, btot);
    k_bscan<<<1, 512, 0, stream>>>(btot, bstart, cursor);
    k_part<<<(NE + PEB - 1) / PEB, 512, 0, stream>>>(ei, cursor, scr);
    k_build<<<NBUK, 256, 0, stream>>>(scr, bstart, rofs, dis, csr);
    k_gemm1<<<NB, 256, 0, stream>>>(x, W1, h1);
    k_gather1<<<(NN * 4 + 255) / 256, 256, 0, stream>>>(rofs, csr, dis, h1, b1, W2, h2);
    k_gather2<<<NB, 256, 0, stream>>>(rofs, csr, dis, h2, b2, out);
}